// Round 9
// baseline (775.394 us; speedup 1.0000x reference)
//
#include <hip/hip_runtime.h>
#include <hip/hip_bf16.h>

#define Bv 8
#define Tv 16
#define Hv 64
#define Wv 64
#define Cv 16
#define HID 64
#define PH 66   // spatially padded (1-px halo)

typedef short short8 __attribute__((ext_vector_type(8)));
typedef float f32x4 __attribute__((ext_vector_type(4)));
typedef unsigned short u16x8 __attribute__((ext_vector_type(8)));

__device__ __forceinline__ unsigned short f2bf(float x) {
  union { float f; unsigned int u; } v; v.f = x;
  unsigned int r = v.u + 0x7FFF + ((v.u >> 16) & 1);   // RNE
  return (unsigned short)(r >> 16);
}
__device__ __forceinline__ float sigmoid_f(float x) {
  return 1.f / (1.f + __expf(-x));
}
__device__ __forceinline__ float tanh_f(float x) {
  float e = __expf(2.f * x);
  return 1.f - 2.f / (e + 1.f);
}

// runtime-n wait (folds to a single s_waitcnt after full unroll)
__device__ __forceinline__ void waitv_rt(int n) {
  if      (n <= 0)  asm volatile("s_waitcnt vmcnt(0)" ::: "memory");
  else if (n == 1)  asm volatile("s_waitcnt vmcnt(1)" ::: "memory");
  else if (n == 2)  asm volatile("s_waitcnt vmcnt(2)" ::: "memory");
  else if (n == 3)  asm volatile("s_waitcnt vmcnt(3)" ::: "memory");
  else if (n == 4)  asm volatile("s_waitcnt vmcnt(4)" ::: "memory");
  else if (n == 5)  asm volatile("s_waitcnt vmcnt(5)" ::: "memory");
  else if (n == 6)  asm volatile("s_waitcnt vmcnt(6)" ::: "memory");
  else if (n == 7)  asm volatile("s_waitcnt vmcnt(7)" ::: "memory");
  else if (n == 8)  asm volatile("s_waitcnt vmcnt(8)" ::: "memory");
  else if (n == 9)  asm volatile("s_waitcnt vmcnt(9)" ::: "memory");
  else if (n == 10) asm volatile("s_waitcnt vmcnt(10)" ::: "memory");
  else if (n == 11) asm volatile("s_waitcnt vmcnt(11)" ::: "memory");
  else              asm volatile("s_waitcnt vmcnt(12)" ::: "memory");
}
// bundle size at iter i: 4 W-loads if W(i+2) exists, 1 A-load if A(i+4) exists
__device__ __forceinline__ constexpr int bS(int i, int NC) {
  return ((i + 2 <= NC - 1) ? 4 : 0) + ((i + 4 <= NC - 1) ? 1 : 0);
}
// safe vmcnt at top of iter cc: ops issued after last-required op
__device__ __forceinline__ constexpr int NWAIT(int cc, int NC) {
  if (cc >= NC - 1) return 0;
  if (cc == 0) return 11;
  if (cc == 1) return 9;
  if (cc == 2) return 10;
  int n = bS(cc - 3, NC) + bS(cc - 2, NC) + bS(cc - 1, NC) - 4;
  return n < 0 ? 0 : n;
}

// ---- weight re-layouts: fp32 [3,3,CI,256] -> bf16 lane-contiguous chunks.
// Chunk cc (16KB): [wn(4)][g(4)][lane(64)][e(8)]; lane l=(kg*16+r) holds
// B[k=kg*8+e][col' = wn*64+g*16+r], orig col = g*64 + wn*16 + r.
__global__ void relayout_w0(const float* __restrict__ W0, unsigned short* __restrict__ out) {
  int o = blockIdx.x * 256 + threadIdx.x;            // 27*8192 = 221184
  if (o >= 27 * 8192) return;
  int cc = o >> 13, t = o & 8191;
  int wn = t >> 11, t2 = t & 2047;
  int g = t2 >> 9, t3 = t2 & 511;
  int l = t3 >> 3, e = t3 & 7;
  int kg = l >> 4, r = l & 15;
  int k = kg * 8 + e;
  int col = g * 64 + wn * 16 + r;
  int tap = cc / 3, cgi = cc - tap * 3;
  int p = cgi * 32 + k;                              // padded ci: 0..15 x, 16..31 pad, 32..95 h
  float v = 0.f;
  if (p < 16)        v = W0[(size_t)(tap * 80 + p) * 256 + col];
  else if (p >= 32)  v = W0[(size_t)(tap * 80 + (p - 16)) * 256 + col];
  out[o] = f2bf(v);
}
__global__ void relayout_w1(const float* __restrict__ W1, unsigned short* __restrict__ out) {
  int o = blockIdx.x * 256 + threadIdx.x;            // 36*8192 = 294912
  if (o >= 36 * 8192) return;
  int cc = o >> 13, t = o & 8191;
  int wn = t >> 11, t2 = t & 2047;
  int g = t2 >> 9, t3 = t2 & 511;
  int l = t3 >> 3, e = t3 & 7;
  int kg = l >> 4, r = l & 15;
  int k = kg * 8 + e;
  int col = g * 64 + wn * 16 + r;
  int tap = cc >> 2, cgi = cc & 3;
  out[o] = f2bf(W1[(size_t)(tap * 128 + cgi * 32 + k) * 256 + col]);
}

// ---- zero only what must be zero per call: x buffer (pads+halo) + h halo rings
__global__ void zero_init(unsigned short* __restrict__ h0a, unsigned short* __restrict__ h0b,
                          unsigned short* __restrict__ h1a, unsigned short* __restrict__ h1b,
                          unsigned short* __restrict__ xb) {
  int idx = blockIdx.x * 256 + threadIdx.x;          // 16B chunks
  u16x8 z = {};
  const int XB_CH = (Bv * PH * PH * 32 * 2) / 16;    // 139392
  if (idx < XB_CH) { *(u16x8*)(xb + idx * 8) = z; return; }
  idx -= XB_CH;
  int bufi = idx / 16640;                            // 8 b x 260 px x 8 chunks
  if (bufi >= 4) return;
  int rem = idx - bufi * 16640;
  int b = rem / 2080, r2 = rem - b * 2080;
  int hp = r2 >> 3, c8 = r2 & 7;
  int y, x;
  if (hp < 66)       { y = 0;  x = hp; }
  else if (hp < 132) { y = 65; x = hp - 66; }
  else { int i2 = hp - 132; y = 1 + (i2 >> 1); x = (i2 & 1) * 65; }
  unsigned short* base = (bufi == 0) ? h0a : (bufi == 1) ? h0b : (bufi == 2) ? h1a : h1b;
  *(u16x8*)(base + ((size_t)((b * PH + y) * PH) + x) * 64 + c8 * 8) = z;
}

// ---- t=0 x conversion: enc fp32 -> padded bf16 [b][66][66][32] (pads pre-zeroed)
__global__ void convert_x0(const float* __restrict__ enc, unsigned short* __restrict__ xb) {
  int idx = blockIdx.x * 256 + threadIdx.x;          // 32768
  int b = idx >> 12, pix = idx & 4095;
  int y = pix >> 6, x = pix & 63;
  const float* s = enc + ((size_t)(b * Tv + 0) * 4096 + pix) * 16;
  float4 f0 = *(const float4*)(s);
  float4 f1 = *(const float4*)(s + 4);
  float4 f2 = *(const float4*)(s + 8);
  float4 f3 = *(const float4*)(s + 12);
  u16x8 o0, o1;
  o0[0]=f2bf(f0.x); o0[1]=f2bf(f0.y); o0[2]=f2bf(f0.z); o0[3]=f2bf(f0.w);
  o0[4]=f2bf(f1.x); o0[5]=f2bf(f1.y); o0[6]=f2bf(f1.z); o0[7]=f2bf(f1.w);
  o1[0]=f2bf(f2.x); o1[1]=f2bf(f2.y); o1[2]=f2bf(f2.z); o1[3]=f2bf(f2.w);
  o1[4]=f2bf(f3.x); o1[5]=f2bf(f3.y); o1[6]=f2bf(f3.z); o1[7]=f2bf(f3.w);
  unsigned short* d = xb + ((size_t)((b * PH + y + 1) * PH) + (x + 1)) * 32;
  *(u16x8*)(d)     = o0;
  *(u16x8*)(d + 8) = o1;
}

// ---- fused ConvLSTM cell step. Block: 128 px (16x8) x 256 gate-cols, 8 waves.
// A (activations): block-cooperative LDS staging, 5 bufs x 8KB, depth-4 gll.
// W (weights): DIRECT global->VGPR (inline asm, ring-4 slots, issued 2 ahead)
//   -- no LDS round-trip: LDS traffic/chunk drops 88KB -> 40KB per CU.
// All loop VMEM hand-issued => exact counted vmcnt (steady 11); lgkmcnt(4)
// proves A-buffer reuse. One raw s_barrier per chunk.
template<int CELL, bool T0>
__global__ __launch_bounds__(512, 2)
void cell_mfma(const unsigned short* __restrict__ A0, const unsigned short* __restrict__ A1,
               const unsigned short* __restrict__ Wr, const float* __restrict__ bias,
               float* __restrict__ cbuf, unsigned short* __restrict__ hout,
               float* __restrict__ h1f, float* __restrict__ c1f,
               const float* __restrict__ enc, int tnext, unsigned short* __restrict__ xnext)
{
  constexpr int NC = T0 ? (CELL == 0 ? 9 : 18) : (CELL == 0 ? 27 : 36);
  extern __shared__ char lds[];                      // 5 x 8KB = 40KB (A only)

  const int tid = threadIdx.x;
  const int l = tid & 63, w = tid >> 6;
  const int wm = w >> 2, wn = w & 3;
  const int gid = blockIdx.x;
  const int bx = gid & 7, by = (gid >> 3) & 3, b = gid >> 5;
  const int r = l & 15, kg = l >> 4;
  const int j = wn * 16 + r;

  const char* bases[2] = {(const char*)A0, (const char*)A1};

  // staging source offsets: wave w stages A px-frag w (pixels w*16 + r)
  int pixs;
  {
    int ps = w * 16 + r;
    int ys = by * 16 + (ps >> 3), xs = bx * 8 + (ps & 7);
    pixs = (b * PH + ys) * PH + xs;                  // tap(0,0) in padded coords
  }

  // ---- early independent loads (bias + c state); drained by first vmcnt wait
  float bi[4];
#pragma unroll
  for (int g = 0; g < 4; ++g) bi[g] = bias[g * 64 + j];
  float cpre[4][4] = {};
  if constexpr (!T0) {
#pragma unroll
    for (int mi = 0; mi < 4; ++mi) {
#pragma unroll
      for (int rg = 0; rg < 4; ++rg) {
        int p = wm * 64 + mi * 16 + kg * 4 + rg;
        int y = by * 16 + (p >> 3), x = bx * 8 + (p & 7);
        cpre[mi][rg] = cbuf[((size_t)((b * Hv + y) * Wv) + x) * HID + j];
      }
    }
  }

  const unsigned long long wbase = (unsigned long long)Wr;
  const unsigned wvo_base = (unsigned)(wn * 4096 + l * 16);

  // chunk cc -> weight chunk index (T0 skips the zero h-operand chunks)
  auto wcc_of = [&](int cc) -> int {
    if (CELL == 0) return T0 ? cc * 3 : cc;
    else           return T0 ? ((cc >> 1) * 4 + (cc & 1)) : cc;
  };

  auto ISSUE_A = [&](int cc, int buf) {
    char* dst = lds + buf * 8192;
    int tap, cgi;
    if (CELL == 0) {
      if (T0) { tap = cc; cgi = 0; }
      else    { tap = cc / 3; cgi = cc - tap * 3; }
    } else {
      if (T0) { tap = cc >> 1; cgi = cc & 1; }
      else    { tap = cc >> 2; cgi = cc & 3; }
    }
    int ky = tap / 3, kx = tap - ky * 3;
    const char* srcb;
    unsigned aoff;
    if (CELL == 0) {
      if (cgi == 0) { srcb = bases[0]; aoff = (unsigned)((pixs + ky * PH + kx) * 64 + kg * 16); }
      else { srcb = bases[1];
             aoff = (unsigned)((pixs + ky * PH + kx) * 128 + ((cgi == 2) ? 64 : 0) + kg * 16); }
    } else {
      srcb = bases[cgi >> 1];
      aoff = (unsigned)((pixs + ky * PH + kx) * 128 + (cgi & 1) * 64 + kg * 16);
    }
    __builtin_amdgcn_global_load_lds((const unsigned int*)(srcb + aoff),
                                     (unsigned int*)(dst + w * 1024), 16, 0, 0);
  };

  short8 bfv[4][4];                                  // W ring: slot = chunk & 3

  auto ISSUE_W = [&](int cc) {
    const int s = cc & 3;
    unsigned vo = wvo_base + (unsigned)(wcc_of(cc) * 16384);
    asm volatile("global_load_dwordx4 %0, %1, %2"
                 : "=&v"(bfv[s][0]) : "v"(vo), "s"(wbase) : "memory");
    asm volatile("global_load_dwordx4 %0, %1, %2 offset:1024"
                 : "=&v"(bfv[s][1]) : "v"(vo), "s"(wbase) : "memory");
    asm volatile("global_load_dwordx4 %0, %1, %2 offset:2048"
                 : "=&v"(bfv[s][2]) : "v"(vo), "s"(wbase) : "memory");
    asm volatile("global_load_dwordx4 %0, %1, %2 offset:3072"
                 : "=&v"(bfv[s][3]) : "v"(vo), "s"(wbase) : "memory");
  };

  f32x4 acc[4][4] = {};
  short8 af[2][4];

  // prologue (issue order pinned: A0..A3, W0, W1)
  ISSUE_A(0, 0); __builtin_amdgcn_sched_barrier(0);
  ISSUE_A(1, 1); __builtin_amdgcn_sched_barrier(0);
  ISSUE_A(2, 2); __builtin_amdgcn_sched_barrier(0);
  ISSUE_A(3, 3); __builtin_amdgcn_sched_barrier(0);
  ISSUE_W(0);    __builtin_amdgcn_sched_barrier(0);
  ISSUE_W(1);    __builtin_amdgcn_sched_barrier(0);

#pragma unroll
  for (int cc = 0; cc < NC; ++cc) {
    waitv_rt(NWAIT(cc, NC));                         // A(cc) + W(cc-1) landed
    __builtin_amdgcn_sched_barrier(0);
    __builtin_amdgcn_s_barrier();                    // raw: no compiler vmcnt drain
    __builtin_amdgcn_sched_barrier(0);

    const int q = cc & 1;
    const char* bufp = lds + (cc % 5) * 8192;
#pragma unroll
    for (int mi = 0; mi < 4; ++mi)
      af[q][mi] = *(const short8*)(bufp + (wm * 4 + mi) * 1024 + l * 16);

    if (cc > 0) {
      asm volatile("s_waitcnt lgkmcnt(4)" ::: "memory");   // chunk cc-1 reads done
      __builtin_amdgcn_sched_barrier(0);
    }
    // bundle order [W(cc+2) x4, A(cc+4)] — pinned (vmcnt formula depends on it)
    if (cc + 2 < NC) ISSUE_W(cc + 2);
    __builtin_amdgcn_sched_barrier(0);
    if (cc + 4 < NC) ISSUE_A(cc + 4, (cc + 4) % 5);  // overwrites freed buf (cc-1)%5
    __builtin_amdgcn_sched_barrier(0);

    if (cc > 0) {
      const int qp = (cc - 1) & 1, sp = (cc - 1) & 3;
#pragma unroll
      for (int mi = 0; mi < 4; ++mi)
#pragma unroll
        for (int g = 0; g < 4; ++g)
          acc[mi][g] = __builtin_amdgcn_mfma_f32_16x16x32_bf16(
              af[qp][mi], bfv[sp][g], acc[mi][g], 0, 0, 0);
    }
  }
  asm volatile("s_waitcnt lgkmcnt(0)" ::: "memory");
  __builtin_amdgcn_sched_barrier(0);
  {
    const int qp = (NC - 1) & 1, sp = (NC - 1) & 3;
#pragma unroll
    for (int mi = 0; mi < 4; ++mi)
#pragma unroll
      for (int g = 0; g < 4; ++g)
        acc[mi][g] = __builtin_amdgcn_mfma_f32_16x16x32_bf16(
            af[qp][mi], bfv[sp][g], acc[mi][g], 0, 0, 0);
  }

  // ---- gates: this wave owns hid j for all 4 gates; c from regs
#pragma unroll
  for (int mi = 0; mi < 4; ++mi) {
#pragma unroll
    for (int rg = 0; rg < 4; ++rg) {
      int p = wm * 64 + mi * 16 + kg * 4 + rg;       // C/D row = (lane>>4)*4 + reg
      int y = by * 16 + (p >> 3), x = bx * 8 + (p & 7);
      float zi = acc[mi][0][rg] + bi[0];
      float zf = acc[mi][1][rg] + bi[1];
      float zo = acc[mi][2][rg] + bi[2];
      float zg = acc[mi][3][rg] + bi[3];
      float co = cpre[mi][rg];
      float cn = sigmoid_f(zf) * co + sigmoid_f(zi) * tanh_f(zg);
      float hn = sigmoid_f(zo) * tanh_f(cn);
      size_t ci = ((size_t)((b * Hv + y) * Wv) + x) * HID + j;
      cbuf[ci] = cn;
      hout[((size_t)((b * PH + y + 1) * PH) + (x + 1)) * HID + j] = f2bf(hn);
      if (CELL == 1 && h1f != nullptr) {
        h1f[ci] = hn;
        c1f[ci] = cn;
      }
    }
  }

  // ---- tail: convert x(tnext) for the next cell0 (cell1 only)
  if (CELL == 1 && tnext < Tv) {
    int px = gid * 128 + (tid >> 2), q4 = tid & 3;
    int bb = px >> 12, pix = px & 4095;
    int y = pix >> 6, x = pix & 63;
    const float* s = enc + ((size_t)(bb * Tv + tnext) * 4096 + pix) * 16 + q4 * 4;
    float4 f = *(const float4*)s;
    unsigned short* d = xnext + ((size_t)((bb * PH + y + 1) * PH) + (x + 1)) * 32 + q4 * 4;
    d[0] = f2bf(f.x); d[1] = f2bf(f.y); d[2] = f2bf(f.z); d[3] = f2bf(f.w);
  }
}

extern "C" void kernel_launch(void* const* d_in, const int* in_sizes, int n_in,
                              void* d_out, int out_size, void* d_ws, size_t ws_size,
                              hipStream_t stream) {
  const float* enc = (const float*)d_in[0];
  const float* W0  = (const float*)d_in[1];
  const float* b0  = (const float*)d_in[2];
  const float* W1  = (const float*)d_in[3];
  const float* b1  = (const float*)d_in[4];

  float* out = (float*)d_out;
  const size_t NST = (size_t)Bv * Hv * Wv * HID;     // 2,097,152
  float* h1f = out;                                   // final h1 (fp32)
  float* c1  = out + NST;                             // c1 running state (fp32, in-place)

  char* ws = (char*)d_ws;
  const size_t SZ_C = NST * 4;                        // 8,388,608
  const size_t SZ_H = (size_t)Bv * PH * PH * HID * 2; // 4,460,544
  const size_t SZ_X = (size_t)Bv * PH * PH * 32 * 2;  // 2,230,272
  float*          c0  = (float*)ws;
  unsigned short* h0a = (unsigned short*)(ws + SZ_C);
  unsigned short* h0b = (unsigned short*)(ws + SZ_C + SZ_H);
  unsigned short* h1a = (unsigned short*)(ws + SZ_C + 2 * SZ_H);
  unsigned short* h1b = (unsigned short*)(ws + SZ_C + 3 * SZ_H);
  unsigned short* xb  = (unsigned short*)(ws + SZ_C + 4 * SZ_H);
  unsigned short* w0r = (unsigned short*)(ws + SZ_C + 4 * SZ_H + SZ_X);
  unsigned short* w1r = (unsigned short*)(ws + SZ_C + 4 * SZ_H + SZ_X + (size_t)27 * 16384);

  hipFuncSetAttribute((const void*)cell_mfma<0,false>, hipFuncAttributeMaxDynamicSharedMemorySize, 65536);
  hipFuncSetAttribute((const void*)cell_mfma<0,true>,  hipFuncAttributeMaxDynamicSharedMemorySize, 65536);
  hipFuncSetAttribute((const void*)cell_mfma<1,false>, hipFuncAttributeMaxDynamicSharedMemorySize, 65536);
  hipFuncSetAttribute((const void*)cell_mfma<1,true>,  hipFuncAttributeMaxDynamicSharedMemorySize, 65536);

  // zero only halos/pads (h state at t=0 handled by T0 chunk-skip; c by T0 c-skip)
  zero_init<<<805, 256, 0, stream>>>(h0a, h0b, h1a, h1b, xb);
  relayout_w0<<<864, 256, 0, stream>>>(W0, w0r);
  relayout_w1<<<1152, 256, 0, stream>>>(W1, w1r);
  convert_x0<<<128, 256, 0, stream>>>(enc, xb);

  dim3 grid(256), block(512);
  for (int t = 0; t < Tv; ++t) {
    const bool last = (t == Tv - 1);
    unsigned short* h0r = (t & 1) ? h0b : h0a;
    unsigned short* h0w = (t & 1) ? h0a : h0b;
    unsigned short* h1r = (t & 1) ? h1b : h1a;
    unsigned short* h1w = (t & 1) ? h1a : h1b;
    if (t == 0) {
      cell_mfma<0,true><<<grid, block, 40960, stream>>>(
          xb, h0r, w0r, b0, c0, h0w, nullptr, nullptr, nullptr, Tv, nullptr);
      cell_mfma<1,true><<<grid, block, 40960, stream>>>(
          h0w, h1r, w1r, b1, c1, h1w, nullptr, nullptr, enc, 1, xb);
    } else {
      cell_mfma<0,false><<<grid, block, 40960, stream>>>(
          xb, h0r, w0r, b0, c0, h0w, nullptr, nullptr, nullptr, Tv, nullptr);
      cell_mfma<1,false><<<grid, block, 40960, stream>>>(
          h0w, h1r, w1r, b1, c1, h1w, last ? h1f : nullptr, last ? c1 : nullptr,
          enc, t + 1, xb);
    }
  }
}

// Round 10
// 746.607 us; speedup vs baseline: 1.0386x; 1.0386x over previous
//
#include <hip/hip_runtime.h>
#include <hip/hip_bf16.h>

#define Bv 8
#define Tv 16
#define Hv 64
#define Wv 64
#define Cv 16
#define HID 64
#define PH 66   // spatially padded (1-px halo)

typedef short short8 __attribute__((ext_vector_type(8)));
typedef float f32x4 __attribute__((ext_vector_type(4)));
typedef unsigned short u16x8 __attribute__((ext_vector_type(8)));

__device__ __forceinline__ unsigned short f2bf(float x) {
  union { float f; unsigned int u; } v; v.f = x;
  unsigned int r = v.u + 0x7FFF + ((v.u >> 16) & 1);   // RNE
  return (unsigned short)(r >> 16);
}
__device__ __forceinline__ float sigmoid_f(float x) {
  return 1.f / (1.f + __expf(-x));
}
__device__ __forceinline__ float tanh_f(float x) {
  float e = __expf(2.f * x);
  return 1.f - 2.f / (e + 1.f);
}
__device__ __forceinline__ void waitv(int n) {   // folds to one s_waitcnt after unroll
  if      (n <= 0) asm volatile("s_waitcnt vmcnt(0)" ::: "memory");
  else if (n == 5) asm volatile("s_waitcnt vmcnt(5)" ::: "memory");
  else             asm volatile("s_waitcnt vmcnt(10)" ::: "memory");
}

// ---- weight re-layouts: fp32 [3,3,CI,256] -> bf16 lane-contiguous chunks.
// Chunk cc (16KB): [wn(4)][g(4)][lane(64)][e(8)]; lane l=(kg*16+r) holds
// B[k=kg*8+e][col' = wn*64+g*16+r], orig col = g*64 + wn*16 + r.
__global__ void relayout_w0(const float* __restrict__ W0, unsigned short* __restrict__ out) {
  int o = blockIdx.x * 256 + threadIdx.x;            // 27*8192 = 221184
  if (o >= 27 * 8192) return;
  int cc = o >> 13, t = o & 8191;
  int wn = t >> 11, t2 = t & 2047;
  int g = t2 >> 9, t3 = t2 & 511;
  int l = t3 >> 3, e = t3 & 7;
  int kg = l >> 4, r = l & 15;
  int k = kg * 8 + e;
  int col = g * 64 + wn * 16 + r;
  int tap = cc / 3, cgi = cc - tap * 3;
  int p = cgi * 32 + k;                              // padded ci: 0..15 x, 16..31 pad, 32..95 h
  float v = 0.f;
  if (p < 16)        v = W0[(size_t)(tap * 80 + p) * 256 + col];
  else if (p >= 32)  v = W0[(size_t)(tap * 80 + (p - 16)) * 256 + col];
  out[o] = f2bf(v);
}
__global__ void relayout_w1(const float* __restrict__ W1, unsigned short* __restrict__ out) {
  int o = blockIdx.x * 256 + threadIdx.x;            // 36*8192 = 294912
  if (o >= 36 * 8192) return;
  int cc = o >> 13, t = o & 8191;
  int wn = t >> 11, t2 = t & 2047;
  int g = t2 >> 9, t3 = t2 & 511;
  int l = t3 >> 3, e = t3 & 7;
  int kg = l >> 4, r = l & 15;
  int k = kg * 8 + e;
  int col = g * 64 + wn * 16 + r;
  int tap = cc >> 2, cgi = cc & 3;
  out[o] = f2bf(W1[(size_t)(tap * 128 + cgi * 32 + k) * 256 + col]);
}

// ---- zero per call: both x buffers (pads+halo) + h halo rings
__global__ void zero_init(unsigned short* __restrict__ h0a, unsigned short* __restrict__ h0b,
                          unsigned short* __restrict__ h1a, unsigned short* __restrict__ h1b,
                          unsigned short* __restrict__ xb) {
  int idx = blockIdx.x * 256 + threadIdx.x;          // 16B chunks
  u16x8 z = {};
  const int XB_CH = (Bv * PH * PH * 32 * 2 * 2) / 16;  // two x buffers = 278784
  if (idx < XB_CH) { *(u16x8*)(xb + idx * 8) = z; return; }
  idx -= XB_CH;
  int bufi = idx / 16640;                            // 8 b x 260 px x 8 chunks
  if (bufi >= 4) return;
  int rem = idx - bufi * 16640;
  int b = rem / 2080, r2 = rem - b * 2080;
  int hp = r2 >> 3, c8 = r2 & 7;
  int y, x;
  if (hp < 66)       { y = 0;  x = hp; }
  else if (hp < 132) { y = 65; x = hp - 66; }
  else { int i2 = hp - 132; y = 1 + (i2 >> 1); x = (i2 & 1) * 65; }
  unsigned short* base = (bufi == 0) ? h0a : (bufi == 1) ? h0b : (bufi == 2) ? h1a : h1b;
  *(u16x8*)(base + ((size_t)((b * PH + y) * PH) + x) * 64 + c8 * 8) = z;
}

// ---- t=0 x conversion: enc fp32 -> padded bf16 [b][66][66][32] (pads pre-zeroed)
__global__ void convert_x0(const float* __restrict__ enc, unsigned short* __restrict__ xb) {
  int idx = blockIdx.x * 256 + threadIdx.x;          // 32768
  int b = idx >> 12, pix = idx & 4095;
  int y = pix >> 6, x = pix & 63;
  const float* s = enc + ((size_t)(b * Tv + 0) * 4096 + pix) * 16;
  float4 f0 = *(const float4*)(s);
  float4 f1 = *(const float4*)(s + 4);
  float4 f2 = *(const float4*)(s + 8);
  float4 f3 = *(const float4*)(s + 12);
  u16x8 o0, o1;
  o0[0]=f2bf(f0.x); o0[1]=f2bf(f0.y); o0[2]=f2bf(f0.z); o0[3]=f2bf(f0.w);
  o0[4]=f2bf(f1.x); o0[5]=f2bf(f1.y); o0[6]=f2bf(f1.z); o0[7]=f2bf(f1.w);
  o1[0]=f2bf(f2.x); o1[1]=f2bf(f2.y); o1[2]=f2bf(f2.z); o1[3]=f2bf(f2.w);
  o1[4]=f2bf(f3.x); o1[5]=f2bf(f3.y); o1[6]=f2bf(f3.z); o1[7]=f2bf(f3.w);
  unsigned short* d = xb + ((size_t)((b * PH + y + 1) * PH) + (x + 1)) * 32;
  *(u16x8*)(d)     = o0;
  *(u16x8*)(d + 8) = o1;
}

// ---- one cell on a 64-px (8x8) tile: 4 waves, wave = 64px x 16hid x 4gates.
// Per K=32 chunk: A 4KB staged once (wave w stages frag w), W 16KB (wave stages
// its own wn slice, read once). 3 LDS bufs x 20KB; in-flight 2 chunks
// (vmcnt(5) steady), raw s_barrier/chunk, lgkmcnt(8) guards buffer reuse.
// NC encodes T0 (zero h-operand chunks skipped): cell0 9|27, cell1 18|36.
template<int CELL, int NC>
__device__ __forceinline__ void cell_run(
    const char* __restrict__ A0, const char* __restrict__ A1,
    const char* __restrict__ Wr, const float* __restrict__ bias,
    float* __restrict__ cbuf, unsigned short* __restrict__ hout,
    float* __restrict__ h1fin, float* __restrict__ c1fin,
    char* lds, int b, int by, int bx, int tid)
{
  constexpr bool T0C = (CELL == 0) ? (NC == 9) : (NC == 18);
  const int l = tid & 63, w = tid >> 6;              // w = wn (gate-col slice)
  const int r = l & 15, kg = l >> 4;
  const int j = w * 16 + r;

  int pixs;                                          // staging: wave w stages frag w
  {
    int ps = w * 16 + r;
    int ys = by * 8 + (ps >> 3), xs = bx * 8 + (ps & 7);
    pixs = (b * PH + ys) * PH + xs;                  // tap(0,0) in padded coords
  }

  float bi[4];
#pragma unroll
  for (int g = 0; g < 4; ++g) bi[g] = bias[g * 64 + j];
  float cpre[4][4] = {};
  if constexpr (!T0C) {
#pragma unroll
    for (int mi = 0; mi < 4; ++mi) {
#pragma unroll
      for (int rg = 0; rg < 4; ++rg) {
        int p = mi * 16 + kg * 4 + rg;
        int y = by * 8 + (p >> 3), x = bx * 8 + (p & 7);
        cpre[mi][rg] = cbuf[((size_t)((b * Hv + y) * Wv) + x) * HID + j];
      }
    }
  }

  auto ISSUE = [&](int cc, int buf) {
    char* dst = lds + buf * 20480;
    int tap, cgi, wcc;
    if (CELL == 0) {
      if (T0C) { tap = cc; cgi = 0; wcc = cc * 3; }
      else     { tap = cc / 3; cgi = cc - tap * 3; wcc = cc; }
    } else {
      if (T0C) { tap = cc >> 1; cgi = cc & 1; wcc = tap * 4 + cgi; }
      else     { tap = cc >> 2; cgi = cc & 3; wcc = cc; }
    }
    int ky = tap / 3, kx = tap - ky * 3;
    const char* srcb;
    unsigned aoff;
    if (CELL == 0) {
      if (cgi == 0) { srcb = A0; aoff = (unsigned)((pixs + ky * PH + kx) * 64 + kg * 16); }
      else { srcb = A1;
             aoff = (unsigned)((pixs + ky * PH + kx) * 128 + ((cgi == 2) ? 64 : 0) + kg * 16); }
    } else {
      srcb = (cgi < 2) ? A0 : A1;
      aoff = (unsigned)((pixs + ky * PH + kx) * 128 + (cgi & 1) * 64 + kg * 16);
    }
    // A frag w (1KB, lane-linear [kg][r][16B])
    __builtin_amdgcn_global_load_lds((const unsigned int*)(srcb + aoff),
                                     (unsigned int*)(dst + w * 1024), 16, 0, 0);
    // W: wave stages its own 4KB wn-slice (identity copy)
    const char* wp = Wr + (size_t)wcc * 16384 + (unsigned)(w * 4096 + l * 16);
#pragma unroll
    for (int k = 0; k < 4; ++k)
      __builtin_amdgcn_global_load_lds((const unsigned int*)(wp + k * 1024),
                                       (unsigned int*)(dst + 4096 + w * 4096 + k * 1024), 16, 0, 0);
  };

  f32x4 acc[4][4] = {};
  short8 af[2][4], bfv[2][4];

  ISSUE(0, 0); ISSUE(1, 1);
#pragma unroll
  for (int cc = 0; cc < NC; ++cc) {
    waitv(cc <= NC - 2 ? 5 : 0);                     // chunk cc landed
    __builtin_amdgcn_sched_barrier(0);
    __builtin_amdgcn_s_barrier();                    // raw: no compiler vmcnt drain
    __builtin_amdgcn_sched_barrier(0);

    const int q = cc & 1;
    const char* bufp = lds + (cc % 3) * 20480;
#pragma unroll
    for (int mi = 0; mi < 4; ++mi)
      af[q][mi] = *(const short8*)(bufp + mi * 1024 + l * 16);
#pragma unroll
    for (int g = 0; g < 4; ++g)
      bfv[q][g] = *(const short8*)(bufp + 4096 + w * 4096 + g * 1024 + l * 16);

    if (cc > 0) {
      asm volatile("s_waitcnt lgkmcnt(8)" ::: "memory");   // chunk cc-1 reads done
      __builtin_amdgcn_sched_barrier(0);
    }
    if (cc + 2 < NC) ISSUE(cc + 2, (cc + 2) % 3);    // overwrites freed buf (cc-1)%3
    __builtin_amdgcn_sched_barrier(0);

    if (cc > 0) {
      const int qp = q ^ 1;
#pragma unroll
      for (int mi = 0; mi < 4; ++mi)
#pragma unroll
        for (int g = 0; g < 4; ++g)
          acc[mi][g] = __builtin_amdgcn_mfma_f32_16x16x32_bf16(
              af[qp][mi], bfv[qp][g], acc[mi][g], 0, 0, 0);
    }
  }
  asm volatile("s_waitcnt lgkmcnt(0)" ::: "memory");
  __builtin_amdgcn_sched_barrier(0);
  {
    const int qp = (NC - 1) & 1;
#pragma unroll
    for (int mi = 0; mi < 4; ++mi)
#pragma unroll
      for (int g = 0; g < 4; ++g)
        acc[mi][g] = __builtin_amdgcn_mfma_f32_16x16x32_bf16(
            af[qp][mi], bfv[qp][g], acc[mi][g], 0, 0, 0);
  }

  // ---- gates: wave owns hid j for all 4 gates; c from regs
#pragma unroll
  for (int mi = 0; mi < 4; ++mi) {
#pragma unroll
    for (int rg = 0; rg < 4; ++rg) {
      int p = mi * 16 + kg * 4 + rg;                 // C/D row = (lane>>4)*4 + reg
      int y = by * 8 + (p >> 3), x = bx * 8 + (p & 7);
      float zi = acc[mi][0][rg] + bi[0];
      float zf = acc[mi][1][rg] + bi[1];
      float zo = acc[mi][2][rg] + bi[2];
      float zg = acc[mi][3][rg] + bi[3];
      float co = cpre[mi][rg];
      float cn = sigmoid_f(zf) * co + sigmoid_f(zi) * tanh_f(zg);
      float hn = sigmoid_f(zo) * tanh_f(cn);
      size_t ci = ((size_t)((b * Hv + y) * Wv) + x) * HID + j;
      cbuf[ci] = cn;
      hout[((size_t)((b * PH + y + 1) * PH) + (x + 1)) * HID + j] = f2bf(hn);
      if (CELL == 1 && h1fin != nullptr) {
        h1fin[ci] = hn;
        c1fin[ci] = cn;
      }
    }
  }
}

// ---- fused dispatch D(t): cell1(t-1) and cell0(t) are INDEPENDENT -> run as
// two block roles in one launch. 256-thr blocks, 60KB LDS -> 2 blocks/CU in
// separate barrier domains (cross-block latency hiding).
template<int NC1, int NC0, bool LAST>
__global__ __launch_bounds__(256, 2)
void step_fused(const unsigned short* __restrict__ xbr, unsigned short* __restrict__ xbw,
                const unsigned short* __restrict__ h0r, unsigned short* __restrict__ h0w,
                const unsigned short* __restrict__ h1r, unsigned short* __restrict__ h1w,
                const unsigned short* __restrict__ w0r, const unsigned short* __restrict__ w1r,
                const float* __restrict__ b0, const float* __restrict__ b1,
                float* __restrict__ c0, float* __restrict__ c1,
                float* __restrict__ h1f, float* __restrict__ c1f,
                const float* __restrict__ enc, int tnext)
{
  extern __shared__ char lds[];
  const int tid = threadIdx.x;
  const int gid = blockIdx.x;
  int isC1, tile;
  if constexpr (NC1 > 0 && NC0 > 0) { isC1 = gid & 1; tile = gid >> 1; }
  else if constexpr (NC1 > 0)       { isC1 = 1; tile = gid; }
  else                              { isC1 = 0; tile = gid; }
  const int b = tile >> 6, rem = tile & 63;
  const int by = rem >> 3, bx = rem & 7;             // 8x8 px tile

  if constexpr (NC1 > 0) {
    if (isC1) {
      cell_run<1, NC1>((const char*)h0r, (const char*)h1r, (const char*)w1r, b1,
                       c1, h1w, LAST ? h1f : nullptr, LAST ? c1f : nullptr,
                       lds, b, by, bx, tid);
      return;
    }
  }
  if constexpr (NC0 > 0) {
    cell_run<0, NC0>((const char*)xbr, (const char*)h0r, (const char*)w0r, b0,
                     c0, h0w, nullptr, nullptr, lds, b, by, bx, tid);
    if (tnext >= 0) {                                // convert own tile of x(tnext)
      int pp = tid >> 2, q4 = tid & 3;
      int y = by * 8 + (pp >> 3), x = bx * 8 + (pp & 7);
      const float* s = enc + ((size_t)(b * Tv + tnext) * 4096 + (y * 64 + x)) * 16 + q4 * 4;
      float4 f = *(const float4*)s;
      unsigned short* d = xbw + ((size_t)((b * PH + y + 1) * PH) + (x + 1)) * 32 + q4 * 4;
      d[0] = f2bf(f.x); d[1] = f2bf(f.y); d[2] = f2bf(f.z); d[3] = f2bf(f.w);
    }
  }
}

extern "C" void kernel_launch(void* const* d_in, const int* in_sizes, int n_in,
                              void* d_out, int out_size, void* d_ws, size_t ws_size,
                              hipStream_t stream) {
  const float* enc = (const float*)d_in[0];
  const float* W0  = (const float*)d_in[1];
  const float* b0  = (const float*)d_in[2];
  const float* W1  = (const float*)d_in[3];
  const float* b1  = (const float*)d_in[4];

  float* out = (float*)d_out;
  const size_t NST = (size_t)Bv * Hv * Wv * HID;     // 2,097,152
  float* h1f = out;                                   // final h1 (fp32)
  float* c1  = out + NST;                             // c1 running state (fp32, in-place)

  char* ws = (char*)d_ws;
  const size_t SZ_C = NST * 4;                        // 8,388,608
  const size_t SZ_H = (size_t)Bv * PH * PH * HID * 2; // 4,460,544
  const size_t SZ_X = (size_t)Bv * PH * PH * 32 * 2;  // 2,230,272
  float*          c0  = (float*)ws;
  unsigned short* h0a = (unsigned short*)(ws + SZ_C);
  unsigned short* h0b = (unsigned short*)(ws + SZ_C + SZ_H);
  unsigned short* h1a = (unsigned short*)(ws + SZ_C + 2 * SZ_H);
  unsigned short* h1b = (unsigned short*)(ws + SZ_C + 3 * SZ_H);
  unsigned short* xb0 = (unsigned short*)(ws + SZ_C + 4 * SZ_H);
  unsigned short* xb1 = (unsigned short*)(ws + SZ_C + 4 * SZ_H + SZ_X);
  unsigned short* w0r = (unsigned short*)(ws + SZ_C + 4 * SZ_H + 2 * SZ_X);
  unsigned short* w1r = (unsigned short*)(ws + SZ_C + 4 * SZ_H + 2 * SZ_X + (size_t)27 * 16384);

  hipFuncSetAttribute((const void*)step_fused<0,9,false>,  hipFuncAttributeMaxDynamicSharedMemorySize, 65536);
  hipFuncSetAttribute((const void*)step_fused<18,27,false>,hipFuncAttributeMaxDynamicSharedMemorySize, 65536);
  hipFuncSetAttribute((const void*)step_fused<36,27,false>,hipFuncAttributeMaxDynamicSharedMemorySize, 65536);
  hipFuncSetAttribute((const void*)step_fused<36,0,true>,  hipFuncAttributeMaxDynamicSharedMemorySize, 65536);

  // zero only halos/pads (t=0 state handled by T0 chunk-skip / c-skip)
  zero_init<<<1349, 256, 0, stream>>>(h0a, h0b, h1a, h1b, xb0);
  relayout_w0<<<864, 256, 0, stream>>>(W0, w0r);
  relayout_w1<<<1152, 256, 0, stream>>>(W1, w1r);
  convert_x0<<<128, 256, 0, stream>>>(enc, xb0);

  const int LDSB = 61440;                            // 3 x 20KB
  // D(0): cell0(0) T0; converts x(1) -> xb1
  step_fused<0,9,false><<<512, 256, LDSB, stream>>>(
      xb0, xb1, h0b, h0a, h1a, h1b, w0r, w1r, b0, b1, c0, c1,
      nullptr, nullptr, enc, 1);
  // D(t), t=1..15: cell1(t-1) || cell0(t) (+ convert x(t+1))
  for (int t = 1; t <= 15; ++t) {
    unsigned short* h0r = (t & 1) ? h0a : h0b;       // h0buf[(t-1)&1]
    unsigned short* h0w = (t & 1) ? h0b : h0a;       // h0buf[t&1]
    unsigned short* h1r = (t & 1) ? h1b : h1a;       // h1buf[t&1] (= h1(t-2))
    unsigned short* h1w = (t & 1) ? h1a : h1b;       // h1buf[(t-1)&1]
    unsigned short* xr  = (t & 1) ? xb1 : xb0;
    unsigned short* xw  = (t & 1) ? xb0 : xb1;
    int tn = (t + 1 <= 15) ? (t + 1) : -1;
    if (t == 1)
      step_fused<18,27,false><<<1024, 256, LDSB, stream>>>(
          xr, xw, h0r, h0w, h1r, h1w, w0r, w1r, b0, b1, c0, c1,
          nullptr, nullptr, enc, tn);
    else
      step_fused<36,27,false><<<1024, 256, LDSB, stream>>>(
          xr, xw, h0r, h0w, h1r, h1w, w0r, w1r, b0, b1, c0, c1,
          nullptr, nullptr, enc, tn);
  }
  // D(16): cell1(15) alone -> writes h1f/c1f
  step_fused<36,0,true><<<512, 256, LDSB, stream>>>(
      xb0, xb1, h0b, h0a, h1a, h1b, w0r, w1r, b0, b1, c0, c1,
      h1f, c1, enc, -1);
}